// Round 14
// baseline (17500.513 us; speedup 1.0000x reference)
//
#include <hip/hip_runtime.h>

// MassConservingLSTM on MI355X — persistent kernel, r9 base + u64-pair stores.
// r13->r14: LDS transpose-stage abandoned (4/4 failures: r10-r13). This round
// is r9 VERBATIM (PASS, 17.4ms) with ONE change: bank stores are paired via a
// single-stage quad butterfly (4x shfl_xor(1) + selects) and written as u64
// __hip_atomic_store (compiler-generated dwordx2 sc0/sc1 — no inline asm).
// Store ops/step: 2.1M -> 1.05M. Finalize/g-build/sync: r9 byte-identical.

#define LSTEPS 1024
#define LOG2E 1.4426950408889634f

typedef unsigned short u16;
typedef unsigned int u32;
typedef unsigned long long u64;
typedef __attribute__((ext_vector_type(8))) short s8v;   // 8 x bf16 (MFMA A/B frag)
typedef __attribute__((ext_vector_type(4))) float f4v;   // MFMA C/D frag

__device__ u32 cnt_mem[4 * 2 * 64];                 // [btile][{step,c2}] counters @256B stride
__device__ float bank_mem[2u * 4 * 64 * 64 * 128];  // [slot][btile][bank(rank)][b][p] 16MB
__device__ float c2pub[2 * 256 * 128];              // [slot][row][128] f32 c2 rows

static __device__ __forceinline__ u16 f2bf(float f) {
  u32 u = __float_as_uint(f);
  u += 0x7fffu + ((u >> 16) & 1u);   // RNE (inputs finite)
  return (u16)(u >> 16);
}

template <typename T>
static __device__ __forceinline__ T ldc(const T* p) {
  return __hip_atomic_load(p, __ATOMIC_RELAXED, __HIP_MEMORY_SCOPE_AGENT);
}
template <typename T>
static __device__ __forceinline__ void stc(T* p, T v) {
  __hip_atomic_store(p, v, __ATOMIC_RELAXED, __HIP_MEMORY_SCOPE_AGENT);
}

static __device__ __forceinline__ void lds_bar() {
  asm volatile("s_waitcnt lgkmcnt(0)" ::: "memory");
  __builtin_amdgcn_s_barrier();
  __builtin_amdgcn_sched_barrier(0);
}
// split wait (arrivals streamed in during previous step)
static __device__ __forceinline__ void wait_cnt(u32* c, u32 target) {
  if (threadIdx.x == 0) {
    while (__hip_atomic_load(c, __ATOMIC_RELAXED, __HIP_MEMORY_SCOPE_AGENT) < target)
      __builtin_amdgcn_s_sleep(2);
  }
  __builtin_amdgcn_s_barrier();
  __builtin_amdgcn_sched_barrier(0);
}
// combined arrive+wait: drain own vmem, arrive, poll, release
static __device__ __forceinline__ void arrive_wait(u32* c, u32 target) {
  asm volatile("s_waitcnt vmcnt(0)" ::: "memory");
  __builtin_amdgcn_s_barrier();
  if (threadIdx.x == 0) {
    __hip_atomic_fetch_add(c, 1u, __ATOMIC_RELAXED, __HIP_MEMORY_SCOPE_AGENT);
    while (__hip_atomic_load(c, __ATOMIC_RELAXED, __HIP_MEMORY_SCOPE_AGENT) < target)
      __builtin_amdgcn_s_sleep(2);
  }
  __builtin_amdgcn_s_barrier();
  __builtin_amdgcn_sched_barrier(0);
}

// ---------------- weight conversion + replay-safe counter reset ----------------
__global__ __launch_bounds__(256) void convert_w_kernel(
    const float* __restrict__ Wr, const float* __restrict__ Wi, const float* __restrict__ Wo,
    u16* __restrict__ WrB, u16* __restrict__ WiB, u16* __restrict__ WoB) {
  if (blockIdx.x == 0)
    for (int i = threadIdx.x; i < 4 * 2 * 64; i += 256) cnt_mem[i] = 0;
  const int n1 = 16384 * 160, n2 = 8192 * 160, n3 = 128 * 160;
  const int stride = gridDim.x * blockDim.x;
  int idx = blockIdx.x * blockDim.x + threadIdx.x;
  for (; idx < n1 + n2 + n3; idx += stride) {
    if (idx < n1)            WrB[idx]           = f2bf(Wr[idx] * LOG2E);
    else if (idx < n1 + n2)  WiB[idx - n1]      = f2bf(Wi[idx - n1] * LOG2E);
    else                     WoB[idx - n1 - n2] = f2bf(Wo[idx - n1 - n2] * (-LOG2E)); // sigmoid via exp2(-x*log2e)
  }
}

// ---------------- persistent kernel ----------------
// 256 WGs x 512 thr. wg = oslot*32 + btile*8 + xcd; rank = oslot*8+xcd in [0,64);
// orow0 = xcd*24 + oslot*3 (3 softmax row-blocks; <128: r-row, else i-row).
// Waves 2x4 over the 64b x 128p tile (r6 orientation: D[b][p]).
__global__ __launch_bounds__(512, 1) void persist_kernel(
    const float* __restrict__ xm, const float* __restrict__ xa,
    const float* __restrict__ br, const float* __restrict__ bi, const float* __restrict__ bo,
    const u16* __restrict__ WrB, const u16* __restrict__ WiB, const u16* __restrict__ WoB,
    float* __restrict__ o_buf,   // [2][256*128] o-gate logits (pre-scaled by -log2e)
    float* __restrict__ hs_out, float* __restrict__ cs_out) {
  __shared__ u16 W_lds[3][128][168];  // resident weights; 336B row stride
  __shared__ u16 g_lds[64][168];
  __shared__ float zex[3][64][4];     // cross-wave softmax-Z exchange (r6)
  __shared__ float c_col[3][64];
  __shared__ float xm_col[3][64];
  __shared__ float red[4][128];       // finalize bank-reduction

  const int tid = threadIdx.x;
  const int wg = blockIdx.x;
  const int xcd = wg & 7;
  const int l32 = wg >> 3;
  const int btile = l32 & 3;
  const int oslot = l32 >> 2;
  const int rank = oslot * 8 + xcd;
  const int orow0 = xcd * 24 + oslot * 3;
  u32* scnt = cnt_mem + (btile * 2 + 0) * 64;
  u32* ccnt = cnt_mem + (btile * 2 + 1) * 64;

  const int lane = tid & 63;
  const int wv = tid >> 6;
  const int wm = wv >> 2;    // b-half
  const int wn = wv & 3;     // p-quarter
  const int lg = lane >> 4;
  const int lc = lane & 15;

  // ---- one-time: stage 3 weight row-blocks into LDS ----
#pragma unroll
  for (int rb = 0; rb < 3; ++rb) {
    const int orow = orow0 + rb;
    const u16* wbp = (orow < 128) ? (WrB + (size_t)orow * 20480)
                                  : (WiB + (size_t)(orow - 128) * 20480);
#pragma unroll
    for (int i = 0; i < 5; ++i) {
      const int chunk = tid + i * 512;
      uint4 v = ((const uint4*)wbp)[chunk];
      *(uint4*)((char*)&W_lds[rb][0][0] + (chunk / 20) * 336 + (chunk % 20) * 16) = v;
    }
  }
  float biasA[3], biasB[3];
#pragma unroll
  for (int task = 0; task < 3; ++task) {
    const int orow = orow0 + task;
    const float* bptr = (orow < 128) ? (br + orow * 128) : (bi + (orow - 128) * 128);
    biasA[task] = bptr[wn * 32 + lc] * LOG2E;
    biasB[task] = bptr[wn * 32 + 16 + lc] * LOG2E;
  }
  const bool duty = (oslot < 4) && (xcd == ((oslot + 2 * btile) & 7)) && (wn == 0);
  const int qoff = (oslot & 3) * 32;
  const float ob0 = bo[qoff + lc] * (-LOG2E);
  const float ob1 = bo[qoff + 16 + lc] * (-LOG2E);

  const int bloc = tid >> 3;
  const int seg = tid & 7;
  const int pseg = seg * 16;
  const int bg = btile * 64 + bloc;

  for (int t = 0; t <= LSTEPS; ++t) {
    // ---- prefetch step-t inputs (pure inputs, barrier-independent) ----
    f4v xa4 = (f4v){0.f, 0.f, 0.f, 0.f};
    float xmv = 0.f;
    if (t < LSTEPS) {
      xa4 = ((const f4v*)(xa + ((size_t)t * 256 + bg) * 32))[seg];
      if (tid < 192) {
        const int col0 = orow0 + (tid >> 6);
        if (col0 >= 128)
          xmv = xm[((size_t)t * 256 + btile * 64 + (tid & 63)) * 64 + (col0 - 128)];
      }
    }

    if (t) wait_cnt(scnt, 64u * (u32)t);  // step t-1 banks + o_buf visible

    const int p = tid & 127;
    float olog = 0.f;

    // ---- finalize pass 1: sum 64 banks for rank row (4 thread-groups x 16 banks) ----
    if (t > 0) {
      const float* B = bank_mem + (size_t)((t - 1) & 1) * 2097152 +
                       (size_t)btile * 524288 + (size_t)rank * 128;
      const int bgi = tid >> 7;
      float s = 0.f;
#pragma unroll
      for (int k = 0; k < 16; ++k) s += ldc(B + (size_t)(bgi * 16 + k) * 8192 + p);
      red[bgi][p] = s;
      if (tid < 128)
        olog = ldc(o_buf + ((t - 1) & 1) * 32768 + (btile * 64 + rank) * 128 + p);
    }
    lds_bar();
    // ---- finalize pass 2: rank row -> h, c2; outputs + publish c2 (f32) ----
    if (t > 0 && tid < 128) {
      float cn = red[0][p] + red[1][p] + red[2][p] + red[3][p];
      float e2 = __builtin_amdgcn_exp2f(olog);
      float og = __builtin_amdgcn_rcpf(1.f + e2);
      float h = og * cn;
      float c2 = cn - h;
      hs_out[((size_t)(t - 1) * 256 + btile * 64 + rank) * 128 + p] = h;
      cs_out[((size_t)(t - 1) * 256 + btile * 64 + rank) * 128 + p] = c2;
      stc(c2pub + (t & 1) * 32768 + (btile * 64 + rank) * 128 + p, c2);
    }
    if (t == LSTEPS) break;  // tail: outputs written, done

    if (t) arrive_wait(ccnt, 64u * (u32)t);  // all 64 c2 rows of this btile visible

    // ---- g-build (r9-verbatim: wide loads + TIED-operand waitcnt) ----
    if (t > 0) {
      const float* ca = c2pub + (t & 1) * 32768 + bg * 128 + pseg;
      f4v cv4[4];
#pragma unroll
      for (int q = 0; q < 4; ++q)
        asm volatile("global_load_dwordx4 %0, %1, off sc0 sc1"
                     : "=v"(cv4[q]) : "v"(ca + q * 4) : "memory");
      asm volatile("s_waitcnt vmcnt(0)"
                   : "+v"(cv4[0]), "+v"(cv4[1]), "+v"(cv4[2]), "+v"(cv4[3])
                   :: "memory");
      float cc[16];
      float csum = 0.f;
#pragma unroll
      for (int q = 0; q < 4; ++q)
#pragma unroll
        for (int j = 0; j < 4; ++j) {
          cc[q * 4 + j] = cv4[q][j];
          csum += cv4[q][j];
        }
      csum += __shfl_xor(csum, 1);
      csum += __shfl_xor(csum, 2);
      csum += __shfl_xor(csum, 4);
      const float sc = (csum == 0.f) ? 1.f : csum;
      const float inv = __builtin_amdgcn_rcpf(sc);
      u32 w[8];
#pragma unroll
      for (int k = 0; k < 8; ++k)
        w[k] = (u32)f2bf(cc[2 * k] * inv) | ((u32)f2bf(cc[2 * k + 1] * inv) << 16);
      uint4* gdst = (uint4*)&g_lds[bloc][32 + pseg];
      gdst[0] = make_uint4(w[0], w[1], w[2], w[3]);
      gdst[1] = make_uint4(w[4], w[5], w[6], w[7]);
    } else {
      uint4* gdst = (uint4*)&g_lds[bloc][32 + pseg];
      gdst[0] = make_uint4(0, 0, 0, 0);
      gdst[1] = make_uint4(0, 0, 0, 0);
    }

    {  // xa -> g cols 0..31
      uint2 pk = make_uint2((u32)f2bf(xa4[0]) | ((u32)f2bf(xa4[1]) << 16),
                            (u32)f2bf(xa4[2]) | ((u32)f2bf(xa4[3]) << 16));
      *(uint2*)&g_lds[bloc][seg * 4] = pk;
    }

    // contraction coefficients for this WG's 3 rows -> LDS
    if (tid < 192) {
      const int task = tid >> 6, bl = tid & 63;
      const int col0 = orow0 + task;
      if (col0 < 128) {
        c_col[task][bl] = (t > 0)
            ? ldc(c2pub + (t & 1) * 32768 + (btile * 64 + bl) * 128 + col0) : 0.f;
      } else {
        xm_col[task][bl] = xmv;
      }
    }
    lds_bar();

    // ---- A fragments pinned for all tasks (r9) ----
    s8v afr[2][5];
#pragma unroll
    for (int mt = 0; mt < 2; ++mt)
#pragma unroll
      for (int ks = 0; ks < 5; ++ks)
        afr[mt][ks] = *(const s8v*)&g_lds[wm * 32 + mt * 16 + lc][ks * 32 + lg * 8];

    // ---- o-gate logits for step t (duty WGs; r9 verbatim) ----
    if (duty) {
      f4v oacc[2][2];
#pragma unroll
      for (int mt = 0; mt < 2; ++mt) {
        oacc[mt][0] = (f4v){ob0, ob0, ob0, ob0};
        oacc[mt][1] = (f4v){ob1, ob1, ob1, ob1};
      }
#pragma unroll
      for (int ks = 0; ks < 5; ++ks) {
        s8v b0 = *(const s8v*)(WoB + (size_t)(qoff + lc) * 160 + ks * 32 + lg * 8);
        s8v b1 = *(const s8v*)(WoB + (size_t)(qoff + 16 + lc) * 160 + ks * 32 + lg * 8);
        oacc[0][0] = __builtin_amdgcn_mfma_f32_16x16x32_bf16(afr[0][ks], b0, oacc[0][0], 0, 0, 0);
        oacc[1][0] = __builtin_amdgcn_mfma_f32_16x16x32_bf16(afr[1][ks], b0, oacc[1][0], 0, 0, 0);
        oacc[0][1] = __builtin_amdgcn_mfma_f32_16x16x32_bf16(afr[0][ks], b1, oacc[0][1], 0, 0, 0);
        oacc[1][1] = __builtin_amdgcn_mfma_f32_16x16x32_bf16(afr[1][ks], b1, oacc[1][1], 0, 0, 0);
      }
      float* ob = o_buf + (t & 1) * 32768;
#pragma unroll
      for (int mt = 0; mt < 2; ++mt)
#pragma unroll
        for (int nt = 0; nt < 2; ++nt)
#pragma unroll
          for (int r = 0; r < 4; ++r)
            stc(&ob[(btile * 64 + wm * 32 + mt * 16 + lg * 4 + r) * 128 + qoff + nt * 16 + lc],
                oacc[mt][nt][r]);
    }

    float cpart[2][2][4] = {};

#pragma unroll
    for (int task = 0; task < 3; ++task) {
      const int orow = orow0 + task;
      const bool is_r = (orow < 128);
      f4v acc[2][2];
#pragma unroll
      for (int mt = 0; mt < 2; ++mt) {
        acc[mt][0] = (f4v){biasA[task], biasA[task], biasA[task], biasA[task]};
        acc[mt][1] = (f4v){biasB[task], biasB[task], biasB[task], biasB[task]};
      }
#pragma unroll
      for (int ks = 0; ks < 5; ++ks) {
        s8v b0 = *(const s8v*)&W_lds[task][wn * 32 + lc][ks * 32 + lg * 8];
        s8v b1 = *(const s8v*)&W_lds[task][wn * 32 + 16 + lc][ks * 32 + lg * 8];
        acc[0][0] = __builtin_amdgcn_mfma_f32_16x16x32_bf16(afr[0][ks], b0, acc[0][0], 0, 0, 0);
        acc[1][0] = __builtin_amdgcn_mfma_f32_16x16x32_bf16(afr[1][ks], b0, acc[1][0], 0, 0, 0);
        acc[0][1] = __builtin_amdgcn_mfma_f32_16x16x32_bf16(afr[0][ks], b1, acc[0][1], 0, 0, 0);
        acc[1][1] = __builtin_amdgcn_mfma_f32_16x16x32_bf16(afr[1][ks], b1, acc[1][1], 0, 0, 0);
      }
      float ev[2][2][4];
      float zp[2][4];
#pragma unroll
      for (int mt = 0; mt < 2; ++mt)
#pragma unroll
        for (int r = 0; r < 4; ++r) {
          float e0 = __builtin_amdgcn_exp2f(acc[mt][0][r]);
          float e1 = __builtin_amdgcn_exp2f(acc[mt][1][r]);
          ev[mt][0][r] = e0;
          ev[mt][1][r] = e1;
          zp[mt][r] = e0 + e1;
        }
#pragma unroll
      for (int mt = 0; mt < 2; ++mt)
#pragma unroll
        for (int r = 0; r < 4; ++r) {
          float z = zp[mt][r];
          z += __shfl_xor(z, 1);
          z += __shfl_xor(z, 2);
          z += __shfl_xor(z, 4);
          z += __shfl_xor(z, 8);
          zp[mt][r] = z;  // 32-col partial per 16-lane group
        }
      if (lc == 0) {
#pragma unroll
        for (int mt = 0; mt < 2; ++mt)
          *(float4*)&zex[task][(wm * 4 + wn) * 8 + mt * 4 + lg][0] =
              make_float4(zp[mt][0], zp[mt][1], zp[mt][2], zp[mt][3]);
      }
      lds_bar();
#pragma unroll
      for (int mt = 0; mt < 2; ++mt) {
        float Z[4] = {0.f, 0.f, 0.f, 0.f};
#pragma unroll
        for (int w2 = 0; w2 < 4; ++w2) {
          float4 v = *(const float4*)&zex[task][(wm * 4 + w2) * 8 + mt * 4 + lg][0];
          Z[0] += v.x; Z[1] += v.y; Z[2] += v.z; Z[3] += v.w;
        }
#pragma unroll
        for (int r = 0; r < 4; ++r) {
          const int brow = wm * 32 + mt * 16 + lg * 4 + r;
          const float cv = is_r ? c_col[task][brow] : xm_col[task][brow];
          const float coef = cv * __builtin_amdgcn_rcpf(Z[r]);
          cpart[mt][0][r] += coef * ev[mt][0][r];
          cpart[mt][1][r] += coef * ev[mt][1][r];
        }
      }
    }

    // ---- bank store: quad butterfly (bit0 swap) -> u64 pair stores (no asm) ----
    // After stage: lane q=lc&3 holds rows {q&1, 2|(q&1)} x col-pair {q&~1,+1}.
    {
      float* bb = bank_mem + (size_t)(t & 1) * 2097152 + (size_t)btile * 524288 +
                  (size_t)rank * 8192;
      const int q1 = lc & 1;
      const int pq0 = wn * 32 + (lc & ~1);  // + nt*16 per nt
#pragma unroll
      for (int mt = 0; mt < 2; ++mt)
#pragma unroll
        for (int nt = 0; nt < 2; ++nt) {
          float a0 = cpart[mt][nt][0], a1 = cpart[mt][nt][1];
          float a2 = cpart[mt][nt][2], a3 = cpart[mt][nt][3];
          float t0 = __shfl_xor(a0, 1), t1 = __shfl_xor(a1, 1);
          float t2 = __shfl_xor(a2, 1), t3 = __shfl_xor(a3, 1);
          float b0 = q1 ? t1 : a0;   // row q1,   col lo
          float b1 = q1 ? a1 : t0;   // row q1,   col hi
          float b2 = q1 ? t3 : a2;   // row 2+q1, col lo
          float b3 = q1 ? a3 : t2;   // row 2+q1, col hi
          const int r1 = wm * 32 + mt * 16 + lg * 4 + q1;
          const int pq = pq0 + nt * 16;
          u64 pk1 = (u64)__float_as_uint(b0) | ((u64)__float_as_uint(b1) << 32);
          u64 pk2 = (u64)__float_as_uint(b2) | ((u64)__float_as_uint(b3) << 32);
          stc((u64*)(bb + (size_t)r1 * 128 + pq), pk1);
          stc((u64*)(bb + (size_t)(r1 + 2) * 128 + pq), pk2);
        }
    }

    // ---- arrive: drain vmem, one counter add ----
    asm volatile("s_waitcnt vmcnt(0)" ::: "memory");
    __builtin_amdgcn_s_barrier();
    __builtin_amdgcn_sched_barrier(0);
    if (tid == 0)
      __hip_atomic_fetch_add(scnt, 1u, __ATOMIC_RELAXED, __HIP_MEMORY_SCOPE_AGENT);
  }
}

// ---------------- fallback: per-step kernel (round-1 proven path, ws-based) ----------------
__global__ __launch_bounds__(512, 2) void step_kernel(
    const float* __restrict__ xm, const float* __restrict__ xa,
    const float* __restrict__ br, const float* __restrict__ bi, const float* __restrict__ bo,
    const u16* __restrict__ WrB, const u16* __restrict__ WiB, const u16* __restrict__ WoB,
    float* __restrict__ c_acc, float* __restrict__ o_buf,
    float* __restrict__ hs_out, float* __restrict__ cs_out, int t) {
  __shared__ u16 W_lds[128][168];
  __shared__ u16 g_lds[64][160];

  const int tid = threadIdx.x;
  const int wg = blockIdx.x;
  const int xcd = wg & 7;
  const int l32 = wg >> 3;
  const int btile = l32 & 3;
  const int oslot = l32 >> 2;
  const int rank = oslot * 8 + xcd;
  const int orow0 = xcd * 24 + oslot * 3;

  const int lane = tid & 63;
  const int wv = tid >> 6;
  const int wm = wv >> 2;
  const int wn = wv & 3;
  const int lg = lane >> 4;
  const int lc = lane & 15;

  if (t < LSTEPS && tid < 32) {
    float4* zb = (float4*)(c_acc + ((t + 1) % 3) * 32768 + wg * 128);
    zb[tid] = make_float4(0.f, 0.f, 0.f, 0.f);
  }

  const int bloc = tid >> 3;
  const int seg = tid & 7;
  const int pseg = seg * 16;
  const int bg = btile * 64 + bloc;

  if (t > 0) {
    const float* ca = c_acc + ((t + 2) % 3) * 32768 + bg * 128 + pseg;
    const float* ol = o_buf + ((t + 1) & 1) * 32768 + bg * 128 + pseg;
    float hv[16], cc[16];
    float csum = 0.f;
#pragma unroll
    for (int q = 0; q < 4; ++q) {
      float4 cn = ((const float4*)ca)[q];
      float4 sl = ((const float4*)ol)[q];
      float cna[4] = {cn.x, cn.y, cn.z, cn.w};
      float sla[4] = {sl.x, sl.y, sl.z, sl.w};
#pragma unroll
      for (int j = 0; j < 4; ++j) {
        float e2 = __builtin_amdgcn_exp2f(sla[j]);
        float og = __builtin_amdgcn_rcpf(1.f + e2);
        float h = og * cna[j];
        float c2 = cna[j] - h;
        hv[q * 4 + j] = h;
        cc[q * 4 + j] = c2;
        csum += c2;
      }
    }
    csum += __shfl_xor(csum, 1);
    csum += __shfl_xor(csum, 2);
    csum += __shfl_xor(csum, 4);
    float sc = (csum == 0.f) ? 1.f : csum;
    float inv = __builtin_amdgcn_rcpf(sc);
    if (bloc == rank) {
      float* ho = hs_out + ((size_t)(t - 1) * 256 + bg) * 128 + pseg;
      float* co = cs_out + ((size_t)(t - 1) * 256 + bg) * 128 + pseg;
#pragma unroll
      for (int q = 0; q < 4; ++q) {
        ((float4*)ho)[q] = make_float4(hv[q * 4], hv[q * 4 + 1], hv[q * 4 + 2], hv[q * 4 + 3]);
        ((float4*)co)[q] = make_float4(cc[q * 4], cc[q * 4 + 1], cc[q * 4 + 2], cc[q * 4 + 3]);
      }
    }
    u32 w[8];
#pragma unroll
    for (int k = 0; k < 8; ++k)
      w[k] = (u32)f2bf(cc[2 * k] * inv) | ((u32)f2bf(cc[2 * k + 1] * inv) << 16);
    uint4* gdst = (uint4*)&g_lds[bloc][32 + pseg];
    gdst[0] = make_uint4(w[0], w[1], w[2], w[3]);
    gdst[1] = make_uint4(w[4], w[5], w[6], w[7]);
  } else {
    uint4* gdst = (uint4*)&g_lds[bloc][32 + pseg];
    gdst[0] = make_uint4(0, 0, 0, 0);
    gdst[1] = make_uint4(0, 0, 0, 0);
  }

  if (t == LSTEPS) return;

  {
    float4 xv = ((const float4*)(xa + ((size_t)t * 256 + bg) * 32))[seg];
    uint2 pk = make_uint2((u32)f2bf(xv.x) | ((u32)f2bf(xv.y) << 16),
                          (u32)f2bf(xv.z) | ((u32)f2bf(xv.w) << 16));
    *(uint2*)&g_lds[bloc][seg * 4] = pk;
  }
  __syncthreads();

  s8v afr[2][5];
#pragma unroll
  for (int mt = 0; mt < 2; ++mt)
#pragma unroll
    for (int ks = 0; ks < 5; ++ks)
      afr[mt][ks] = *(const s8v*)&g_lds[wm * 32 + mt * 16 + lc][ks * 32 + lg * 8];

  float cpart[2][2][4] = {};
  const float* cprev = c_acc + ((t + 2) % 3) * 32768;
  const float* oprev = o_buf + ((t + 1) & 1) * 32768;

  uint4 pf[5];
  {
    const u16* wbp = (orow0 < 128) ? (WrB + (size_t)orow0 * 20480)
                                   : (WiB + (size_t)(orow0 - 128) * 20480);
#pragma unroll
    for (int i = 0; i < 5; ++i) pf[i] = ((const uint4*)wbp)[tid + i * 512];
  }
#pragma unroll
  for (int i = 0; i < 5; ++i) {
    int chunk = tid + i * 512;
    *(uint4*)((char*)&W_lds[0][0] + (chunk / 20) * 336 + (chunk % 20) * 16) = pf[i];
  }
  __syncthreads();

  for (int task = 0; task < 3; ++task) {
    const int orow = orow0 + task;
    const bool is_r = (orow < 128);
    if (task < 2) {
      const int nr = orow + 1;
      const u16* wbp = (nr < 128) ? (WrB + (size_t)nr * 20480)
                                  : (WiB + (size_t)(nr - 128) * 20480);
#pragma unroll
      for (int i = 0; i < 5; ++i) pf[i] = ((const uint4*)wbp)[tid + i * 512];
    }
    const float* bptr = is_r ? (br + orow * 128) : (bi + (orow - 128) * 128);
    float bias0 = bptr[wn * 32 + lc] * LOG2E;
    float bias1 = bptr[wn * 32 + 16 + lc] * LOG2E;
    f4v acc[2][2];
#pragma unroll
    for (int mt = 0; mt < 2; ++mt) {
      acc[mt][0] = (f4v){bias0, bias0, bias0, bias0};
      acc[mt][1] = (f4v){bias1, bias1, bias1, bias1};
    }
#pragma unroll
    for (int ks = 0; ks < 5; ++ks) {
      s8v b0 = *(const s8v*)&W_lds[wn * 32 + lc][ks * 32 + lg * 8];
      s8v b1 = *(const s8v*)&W_lds[wn * 32 + 16 + lc][ks * 32 + lg * 8];
      acc[0][0] = __builtin_amdgcn_mfma_f32_16x16x32_bf16(afr[0][ks], b0, acc[0][0], 0, 0, 0);
      acc[1][0] = __builtin_amdgcn_mfma_f32_16x16x32_bf16(afr[1][ks], b0, acc[1][0], 0, 0, 0);
      acc[0][1] = __builtin_amdgcn_mfma_f32_16x16x32_bf16(afr[0][ks], b1, acc[0][1], 0, 0, 0);
      acc[1][1] = __builtin_amdgcn_mfma_f32_16x16x32_bf16(afr[1][ks], b1, acc[1][1], 0, 0, 0);
    }
    float ev[2][2][4];
    float zp[2][4];
#pragma unroll
    for (int mt = 0; mt < 2; ++mt)
#pragma unroll
      for (int r = 0; r < 4; ++r) {
        float e0 = __builtin_amdgcn_exp2f(acc[mt][0][r]);
        float e1 = __builtin_amdgcn_exp2f(acc[mt][1][r]);
        ev[mt][0][r] = e0;
        ev[mt][1][r] = e1;
        zp[mt][r] = e0 + e1;
      }
#pragma unroll
    for (int mt = 0; mt < 2; ++mt)
#pragma unroll
      for (int r = 0; r < 4; ++r) {
        float z = zp[mt][r];
        z += __shfl_xor(z, 1);
        z += __shfl_xor(z, 2);
        z += __shfl_xor(z, 4);
        z += __shfl_xor(z, 8);
        zp[mt][r] = z;
      }
    if (lc == 0) {
#pragma unroll
      for (int mt = 0; mt < 2; ++mt)
        *(float4*)((char*)&W_lds[0][0] + ((wm * 4 + wn) * 8 + mt * 4 + lg) * 336 + 320) =
            make_float4(zp[mt][0], zp[mt][1], zp[mt][2], zp[mt][3]);
    }
    __syncthreads();
#pragma unroll
    for (int mt = 0; mt < 2; ++mt) {
      float Z[4] = {0.f, 0.f, 0.f, 0.f};
#pragma unroll
      for (int w2 = 0; w2 < 4; ++w2) {
        float4 v = *(const float4*)((char*)&W_lds[0][0] + ((wm * 4 + w2) * 8 + mt * 4 + lg) * 336 + 320);
        Z[0] += v.x; Z[1] += v.y; Z[2] += v.z; Z[3] += v.w;
      }
#pragma unroll
      for (int r = 0; r < 4; ++r) {
        const int brow = wm * 32 + mt * 16 + lg * 4 + r;
        const int bg2 = btile * 64 + brow;
        float cv;
        if (is_r) {
          if (t > 0) {
            float cn = cprev[bg2 * 128 + orow];
            float s2 = oprev[bg2 * 128 + orow];
            float e2 = __builtin_amdgcn_exp2f(s2);
            cv = cn * e2 * __builtin_amdgcn_rcpf(1.f + e2);
          } else cv = 0.f;
        } else {
          cv = xm[((size_t)t * 256 + bg2) * 64 + (orow - 128)];
        }
        float coef = cv * __builtin_amdgcn_rcpf(Z[r]);
        cpart[mt][0][r] += coef * ev[mt][0][r];
        cpart[mt][1][r] += coef * ev[mt][1][r];
      }
    }
    if (task < 2) {
#pragma unroll
      for (int i = 0; i < 5; ++i) {
        int chunk = tid + i * 512;
        *(uint4*)((char*)&W_lds[0][0] + (chunk / 20) * 336 + (chunk % 20) * 16) = pf[i];
      }
      __syncthreads();
    }
  }

  if (oslot < 4 && xcd == ((oslot + 2 * btile) & 7) && wn == 0) {
    const int qoff = oslot * 32;
    float ob0 = bo[qoff + lc] * (-LOG2E);
    float ob1 = bo[qoff + 16 + lc] * (-LOG2E);
    f4v oacc[2][2];
#pragma unroll
    for (int mt = 0; mt < 2; ++mt) {
      oacc[mt][0] = (f4v){ob0, ob0, ob0, ob0};
      oacc[mt][1] = (f4v){ob1, ob1, ob1, ob1};
    }
#pragma unroll
    for (int ks = 0; ks < 5; ++ks) {
      s8v b0 = *(const s8v*)(WoB + (size_t)(qoff + lc) * 160 + ks * 32 + lg * 8);
      s8v b1 = *(const s8v*)(WoB + (size_t)(qoff + 16 + lc) * 160 + ks * 32 + lg * 8);
      oacc[0][0] = __builtin_amdgcn_mfma_f32_16x16x32_bf16(afr[0][ks], b0, oacc[0][0], 0, 0, 0);
      oacc[1][0] = __builtin_amdgcn_mfma_f32_16x16x32_bf16(afr[1][ks], b0, oacc[1][0], 0, 0, 0);
      oacc[0][1] = __builtin_amdgcn_mfma_f32_16x16x32_bf16(afr[0][ks], b1, oacc[0][1], 0, 0, 0);
      oacc[1][1] = __builtin_amdgcn_mfma_f32_16x16x32_bf16(afr[1][ks], b1, oacc[1][1], 0, 0, 0);
    }
    float* ob = o_buf + (t & 1) * 32768;
#pragma unroll
    for (int mt = 0; mt < 2; ++mt)
#pragma unroll
      for (int nt = 0; nt < 2; ++nt)
#pragma unroll
        for (int r = 0; r < 4; ++r)
          ob[(btile * 64 + wm * 32 + mt * 16 + lg * 4 + r) * 128 + qoff + nt * 16 + lc] = oacc[mt][nt][r];
  }

  float* cb = c_acc + (t % 3) * 32768;
#pragma unroll
  for (int mt = 0; mt < 2; ++mt)
#pragma unroll
    for (int nt = 0; nt < 2; ++nt)
#pragma unroll
      for (int r = 0; r < 4; ++r)
        unsafeAtomicAdd(&cb[(btile * 64 + wm * 32 + mt * 16 + lg * 4 + r) * 128 + wn * 32 + nt * 16 + lc],
                        cpart[mt][nt][r]);
}

extern "C" void kernel_launch(void* const* d_in, const int* in_sizes, int n_in,
                              void* d_out, int out_size, void* d_ws, size_t ws_size,
                              hipStream_t stream) {
  const float* xm = (const float*)d_in[0];
  const float* xa = (const float*)d_in[1];
  const float* Wr = (const float*)d_in[2];
  const float* br = (const float*)d_in[3];
  const float* Wi = (const float*)d_in[4];
  const float* bi = (const float*)d_in[5];
  const float* Wo = (const float*)d_in[6];
  const float* bo = (const float*)d_in[7];

  if (ws_size < 8560640) return;
  u16* WrB = (u16*)d_ws;
  u16* WiB = WrB + 16384 * 160;
  u16* WoB = WiB + 8192 * 160;
  float* c_acc = (float*)(WoB + 128 * 160);  // fallback-path accumulator
  float* o_buf = c_acc + 3 * 32768;

  float* hs = (float*)d_out;
  float* cs = hs + (size_t)LSTEPS * 256 * 128;

  convert_w_kernel<<<dim3(1024), dim3(256), 0, stream>>>(Wr, Wi, Wo, WrB, WiB, WoB);
  (void)hipMemsetAsync(c_acc, 0, 3 * 32768 * sizeof(float), stream);

  void* kargs[] = {(void*)&xm, (void*)&xa, (void*)&br, (void*)&bi, (void*)&bo,
                   (void*)&WrB, (void*)&WiB, (void*)&WoB,
                   (void*)&o_buf, (void*)&hs, (void*)&cs};
  hipError_t st = hipLaunchCooperativeKernel((const void*)persist_kernel, dim3(256), dim3(512),
                                             kargs, 0, stream);
  if (st != hipSuccess) {  // fallback: proven per-step path
    for (int t = 0; t <= LSTEPS; ++t)
      step_kernel<<<dim3(256), dim3(512), 0, stream>>>(xm, xa, br, bi, bo, WrB, WiB, WoB,
                                                       c_acc, o_buf, hs, cs, t);
  }
}

// Round 15
// 15458.632 us; speedup vs baseline: 1.1321x; 1.1321x over previous
//
#include <hip/hip_runtime.h>

// MassConservingLSTM on MI355X — persistent kernel, hierarchical sync counters.
// r14->r15: r14 PASS base (17.5ms) + sync-path-only changes:
//  (1) per-btile counters split into 8 per-oslot sub-counters (own cache lines):
//      arrive contention 64->8 serialized RMWs; wait = 8 threads poll in parallel.
//  (2) hs/cs output stores deferred past the ccnt sync (drain at end-of-step).
//  (3) s_sleep(2) -> s_sleep(1).
// Numerics byte-identical to r14 (absmax 0.03125).

#define LSTEPS 1024
#define LOG2E 1.4426950408889634f

typedef unsigned short u16;
typedef unsigned int u32;
typedef unsigned long long u64;
typedef __attribute__((ext_vector_type(8))) short s8v;   // 8 x bf16 (MFMA A/B frag)
typedef __attribute__((ext_vector_type(4))) float f4v;   // MFMA C/D frag

__device__ u32 cnt_mem[4 * 2 * 8 * 64];             // [btile][{step,c2}][oslot] @256B stride
__device__ float bank_mem[2u * 4 * 64 * 64 * 128];  // [slot][btile][bank(rank)][b][p] 16MB
__device__ float c2pub[2 * 256 * 128];              // [slot][row][128] f32 c2 rows

static __device__ __forceinline__ u16 f2bf(float f) {
  u32 u = __float_as_uint(f);
  u += 0x7fffu + ((u >> 16) & 1u);   // RNE (inputs finite)
  return (u16)(u >> 16);
}

template <typename T>
static __device__ __forceinline__ T ldc(const T* p) {
  return __hip_atomic_load(p, __ATOMIC_RELAXED, __HIP_MEMORY_SCOPE_AGENT);
}
template <typename T>
static __device__ __forceinline__ void stc(T* p, T v) {
  __hip_atomic_store(p, v, __ATOMIC_RELAXED, __HIP_MEMORY_SCOPE_AGENT);
}

static __device__ __forceinline__ void lds_bar() {
  asm volatile("s_waitcnt lgkmcnt(0)" ::: "memory");
  __builtin_amdgcn_s_barrier();
  __builtin_amdgcn_sched_barrier(0);
}
// hierarchical wait: threads 0..7 poll the 8 per-oslot sub-counters in parallel
static __device__ __forceinline__ void wait_cnt8(u32* c, u32 target) {
  if (threadIdx.x < 8) {
    while (__hip_atomic_load(c + threadIdx.x * 64, __ATOMIC_RELAXED,
                             __HIP_MEMORY_SCOPE_AGENT) < target)
      __builtin_amdgcn_s_sleep(1);
  }
  __builtin_amdgcn_s_barrier();
  __builtin_amdgcn_sched_barrier(0);
}
// hierarchical arrive+wait: drain own vmem, add to own oslot line, poll all 8
static __device__ __forceinline__ void arrive_wait8(u32* c, int oslot, u32 target) {
  asm volatile("s_waitcnt vmcnt(0)" ::: "memory");
  __builtin_amdgcn_s_barrier();
  if (threadIdx.x == 0)
    __hip_atomic_fetch_add(c + oslot * 64, 1u, __ATOMIC_RELAXED, __HIP_MEMORY_SCOPE_AGENT);
  if (threadIdx.x < 8) {
    while (__hip_atomic_load(c + threadIdx.x * 64, __ATOMIC_RELAXED,
                             __HIP_MEMORY_SCOPE_AGENT) < target)
      __builtin_amdgcn_s_sleep(1);
  }
  __builtin_amdgcn_s_barrier();
  __builtin_amdgcn_sched_barrier(0);
}

// ---------------- weight conversion + replay-safe counter reset ----------------
__global__ __launch_bounds__(256) void convert_w_kernel(
    const float* __restrict__ Wr, const float* __restrict__ Wi, const float* __restrict__ Wo,
    u16* __restrict__ WrB, u16* __restrict__ WiB, u16* __restrict__ WoB) {
  if (blockIdx.x == 0)
    for (int i = threadIdx.x; i < 4 * 2 * 8 * 64; i += 256) cnt_mem[i] = 0;
  const int n1 = 16384 * 160, n2 = 8192 * 160, n3 = 128 * 160;
  const int stride = gridDim.x * blockDim.x;
  int idx = blockIdx.x * blockDim.x + threadIdx.x;
  for (; idx < n1 + n2 + n3; idx += stride) {
    if (idx < n1)            WrB[idx]           = f2bf(Wr[idx] * LOG2E);
    else if (idx < n1 + n2)  WiB[idx - n1]      = f2bf(Wi[idx - n1] * LOG2E);
    else                     WoB[idx - n1 - n2] = f2bf(Wo[idx - n1 - n2] * (-LOG2E)); // sigmoid via exp2(-x*log2e)
  }
}

// ---------------- persistent kernel ----------------
// 256 WGs x 512 thr. wg = oslot*32 + btile*8 + xcd; rank = oslot*8+xcd in [0,64);
// orow0 = xcd*24 + oslot*3 (3 softmax row-blocks; <128: r-row, else i-row).
// Waves 2x4 over the 64b x 128p tile (r6 orientation: D[b][p]).
__global__ __launch_bounds__(512, 1) void persist_kernel(
    const float* __restrict__ xm, const float* __restrict__ xa,
    const float* __restrict__ br, const float* __restrict__ bi, const float* __restrict__ bo,
    const u16* __restrict__ WrB, const u16* __restrict__ WiB, const u16* __restrict__ WoB,
    float* __restrict__ o_buf,   // [2][256*128] o-gate logits (pre-scaled by -log2e)
    float* __restrict__ hs_out, float* __restrict__ cs_out) {
  __shared__ u16 W_lds[3][128][168];  // resident weights; 336B row stride
  __shared__ u16 g_lds[64][168];
  __shared__ float zex[3][64][4];     // cross-wave softmax-Z exchange (r6)
  __shared__ float c_col[3][64];
  __shared__ float xm_col[3][64];
  __shared__ float red[4][128];       // finalize bank-reduction

  const int tid = threadIdx.x;
  const int wg = blockIdx.x;
  const int xcd = wg & 7;
  const int l32 = wg >> 3;
  const int btile = l32 & 3;
  const int oslot = l32 >> 2;
  const int rank = oslot * 8 + xcd;
  const int orow0 = xcd * 24 + oslot * 3;
  u32* scnt = cnt_mem + (btile * 2 + 0) * 8 * 64;
  u32* ccnt = cnt_mem + (btile * 2 + 1) * 8 * 64;

  const int lane = tid & 63;
  const int wv = tid >> 6;
  const int wm = wv >> 2;    // b-half
  const int wn = wv & 3;     // p-quarter
  const int lg = lane >> 4;
  const int lc = lane & 15;

  // ---- one-time: stage 3 weight row-blocks into LDS ----
#pragma unroll
  for (int rb = 0; rb < 3; ++rb) {
    const int orow = orow0 + rb;
    const u16* wbp = (orow < 128) ? (WrB + (size_t)orow * 20480)
                                  : (WiB + (size_t)(orow - 128) * 20480);
#pragma unroll
    for (int i = 0; i < 5; ++i) {
      const int chunk = tid + i * 512;
      uint4 v = ((const uint4*)wbp)[chunk];
      *(uint4*)((char*)&W_lds[rb][0][0] + (chunk / 20) * 336 + (chunk % 20) * 16) = v;
    }
  }
  float biasA[3], biasB[3];
#pragma unroll
  for (int task = 0; task < 3; ++task) {
    const int orow = orow0 + task;
    const float* bptr = (orow < 128) ? (br + orow * 128) : (bi + (orow - 128) * 128);
    biasA[task] = bptr[wn * 32 + lc] * LOG2E;
    biasB[task] = bptr[wn * 32 + 16 + lc] * LOG2E;
  }
  const bool duty = (oslot < 4) && (xcd == ((oslot + 2 * btile) & 7)) && (wn == 0);
  const int qoff = (oslot & 3) * 32;
  const float ob0 = bo[qoff + lc] * (-LOG2E);
  const float ob1 = bo[qoff + 16 + lc] * (-LOG2E);

  const int bloc = tid >> 3;
  const int seg = tid & 7;
  const int pseg = seg * 16;
  const int bg = btile * 64 + bloc;

  for (int t = 0; t <= LSTEPS; ++t) {
    // ---- prefetch step-t inputs (pure inputs, barrier-independent) ----
    f4v xa4 = (f4v){0.f, 0.f, 0.f, 0.f};
    float xmv = 0.f;
    if (t < LSTEPS) {
      xa4 = ((const f4v*)(xa + ((size_t)t * 256 + bg) * 32))[seg];
      if (tid < 192) {
        const int col0 = orow0 + (tid >> 6);
        if (col0 >= 128)
          xmv = xm[((size_t)t * 256 + btile * 64 + (tid & 63)) * 64 + (col0 - 128)];
      }
    }

    if (t) wait_cnt8(scnt, 8u * (u32)t);  // step t-1 banks + o_buf visible

    const int p = tid & 127;
    float olog = 0.f, hOut = 0.f, c2Out = 0.f;

    // ---- finalize pass 1: sum 64 banks for rank row (4 thread-groups x 16 banks) ----
    if (t > 0) {
      const float* B = bank_mem + (size_t)((t - 1) & 1) * 2097152 +
                       (size_t)btile * 524288 + (size_t)rank * 128;
      const int bgi = tid >> 7;
      float s = 0.f;
#pragma unroll
      for (int k = 0; k < 16; ++k) s += ldc(B + (size_t)(bgi * 16 + k) * 8192 + p);
      red[bgi][p] = s;
      if (tid < 128)
        olog = ldc(o_buf + ((t - 1) & 1) * 32768 + (btile * 64 + rank) * 128 + p);
    }
    lds_bar();
    // ---- finalize pass 2: rank row -> h, c2 (registers); publish c2 (f32) ----
    if (t > 0 && tid < 128) {
      float cn = red[0][p] + red[1][p] + red[2][p] + red[3][p];
      float e2 = __builtin_amdgcn_exp2f(olog);
      float og = __builtin_amdgcn_rcpf(1.f + e2);
      hOut = og * cn;
      c2Out = cn - hOut;
      stc(c2pub + (t & 1) * 32768 + (btile * 64 + rank) * 128 + p, c2Out);
    }
    if (t == LSTEPS) {  // tail: write final outputs, done
      if (tid < 128) {
        hs_out[((size_t)(t - 1) * 256 + btile * 64 + rank) * 128 + p] = hOut;
        cs_out[((size_t)(t - 1) * 256 + btile * 64 + rank) * 128 + p] = c2Out;
      }
      break;
    }

    if (t) arrive_wait8(ccnt, oslot, 8u * (u32)t);  // all 64 c2 rows visible

    // ---- g-build (r9-verbatim: wide loads + TIED-operand waitcnt) ----
    if (t > 0) {
      const float* ca = c2pub + (t & 1) * 32768 + bg * 128 + pseg;
      f4v cv4[4];
#pragma unroll
      for (int q = 0; q < 4; ++q)
        asm volatile("global_load_dwordx4 %0, %1, off sc0 sc1"
                     : "=v"(cv4[q]) : "v"(ca + q * 4) : "memory");
      asm volatile("s_waitcnt vmcnt(0)"
                   : "+v"(cv4[0]), "+v"(cv4[1]), "+v"(cv4[2]), "+v"(cv4[3])
                   :: "memory");
      float cc[16];
      float csum = 0.f;
#pragma unroll
      for (int q = 0; q < 4; ++q)
#pragma unroll
        for (int j = 0; j < 4; ++j) {
          cc[q * 4 + j] = cv4[q][j];
          csum += cv4[q][j];
        }
      csum += __shfl_xor(csum, 1);
      csum += __shfl_xor(csum, 2);
      csum += __shfl_xor(csum, 4);
      const float sc = (csum == 0.f) ? 1.f : csum;
      const float inv = __builtin_amdgcn_rcpf(sc);
      u32 w[8];
#pragma unroll
      for (int k = 0; k < 8; ++k)
        w[k] = (u32)f2bf(cc[2 * k] * inv) | ((u32)f2bf(cc[2 * k + 1] * inv) << 16);
      uint4* gdst = (uint4*)&g_lds[bloc][32 + pseg];
      gdst[0] = make_uint4(w[0], w[1], w[2], w[3]);
      gdst[1] = make_uint4(w[4], w[5], w[6], w[7]);
    } else {
      uint4* gdst = (uint4*)&g_lds[bloc][32 + pseg];
      gdst[0] = make_uint4(0, 0, 0, 0);
      gdst[1] = make_uint4(0, 0, 0, 0);
    }

    {  // xa -> g cols 0..31
      uint2 pk = make_uint2((u32)f2bf(xa4[0]) | ((u32)f2bf(xa4[1]) << 16),
                            (u32)f2bf(xa4[2]) | ((u32)f2bf(xa4[3]) << 16));
      *(uint2*)&g_lds[bloc][seg * 4] = pk;
    }

    // contraction coefficients for this WG's 3 rows -> LDS
    if (tid < 192) {
      const int task = tid >> 6, bl = tid & 63;
      const int col0 = orow0 + task;
      if (col0 < 128) {
        c_col[task][bl] = (t > 0)
            ? ldc(c2pub + (t & 1) * 32768 + (btile * 64 + bl) * 128 + col0) : 0.f;
      } else {
        xm_col[task][bl] = xmv;
      }
    }
    lds_bar();

    // ---- A fragments pinned for all tasks (r9) ----
    s8v afr[2][5];
#pragma unroll
    for (int mt = 0; mt < 2; ++mt)
#pragma unroll
      for (int ks = 0; ks < 5; ++ks)
        afr[mt][ks] = *(const s8v*)&g_lds[wm * 32 + mt * 16 + lc][ks * 32 + lg * 8];

    // ---- o-gate logits for step t (duty WGs; r9 verbatim) ----
    if (duty) {
      f4v oacc[2][2];
#pragma unroll
      for (int mt = 0; mt < 2; ++mt) {
        oacc[mt][0] = (f4v){ob0, ob0, ob0, ob0};
        oacc[mt][1] = (f4v){ob1, ob1, ob1, ob1};
      }
#pragma unroll
      for (int ks = 0; ks < 5; ++ks) {
        s8v b0 = *(const s8v*)(WoB + (size_t)(qoff + lc) * 160 + ks * 32 + lg * 8);
        s8v b1 = *(const s8v*)(WoB + (size_t)(qoff + 16 + lc) * 160 + ks * 32 + lg * 8);
        oacc[0][0] = __builtin_amdgcn_mfma_f32_16x16x32_bf16(afr[0][ks], b0, oacc[0][0], 0, 0, 0);
        oacc[1][0] = __builtin_amdgcn_mfma_f32_16x16x32_bf16(afr[1][ks], b0, oacc[1][0], 0, 0, 0);
        oacc[0][1] = __builtin_amdgcn_mfma_f32_16x16x32_bf16(afr[0][ks], b1, oacc[0][1], 0, 0, 0);
        oacc[1][1] = __builtin_amdgcn_mfma_f32_16x16x32_bf16(afr[1][ks], b1, oacc[1][1], 0, 0, 0);
      }
      float* ob = o_buf + (t & 1) * 32768;
#pragma unroll
      for (int mt = 0; mt < 2; ++mt)
#pragma unroll
        for (int nt = 0; nt < 2; ++nt)
#pragma unroll
          for (int r = 0; r < 4; ++r)
            stc(&ob[(btile * 64 + wm * 32 + mt * 16 + lg * 4 + r) * 128 + qoff + nt * 16 + lc],
                oacc[mt][nt][r]);
    }

    float cpart[2][2][4] = {};

#pragma unroll
    for (int task = 0; task < 3; ++task) {
      const int orow = orow0 + task;
      const bool is_r = (orow < 128);
      f4v acc[2][2];
#pragma unroll
      for (int mt = 0; mt < 2; ++mt) {
        acc[mt][0] = (f4v){biasA[task], biasA[task], biasA[task], biasA[task]};
        acc[mt][1] = (f4v){biasB[task], biasB[task], biasB[task], biasB[task]};
      }
#pragma unroll
      for (int ks = 0; ks < 5; ++ks) {
        s8v b0 = *(const s8v*)&W_lds[task][wn * 32 + lc][ks * 32 + lg * 8];
        s8v b1 = *(const s8v*)&W_lds[task][wn * 32 + 16 + lc][ks * 32 + lg * 8];
        acc[0][0] = __builtin_amdgcn_mfma_f32_16x16x32_bf16(afr[0][ks], b0, acc[0][0], 0, 0, 0);
        acc[1][0] = __builtin_amdgcn_mfma_f32_16x16x32_bf16(afr[1][ks], b0, acc[1][0], 0, 0, 0);
        acc[0][1] = __builtin_amdgcn_mfma_f32_16x16x32_bf16(afr[0][ks], b1, acc[0][1], 0, 0, 0);
        acc[1][1] = __builtin_amdgcn_mfma_f32_16x16x32_bf16(afr[1][ks], b1, acc[1][1], 0, 0, 0);
      }
      float ev[2][2][4];
      float zp[2][4];
#pragma unroll
      for (int mt = 0; mt < 2; ++mt)
#pragma unroll
        for (int r = 0; r < 4; ++r) {
          float e0 = __builtin_amdgcn_exp2f(acc[mt][0][r]);
          float e1 = __builtin_amdgcn_exp2f(acc[mt][1][r]);
          ev[mt][0][r] = e0;
          ev[mt][1][r] = e1;
          zp[mt][r] = e0 + e1;
        }
#pragma unroll
      for (int mt = 0; mt < 2; ++mt)
#pragma unroll
        for (int r = 0; r < 4; ++r) {
          float z = zp[mt][r];
          z += __shfl_xor(z, 1);
          z += __shfl_xor(z, 2);
          z += __shfl_xor(z, 4);
          z += __shfl_xor(z, 8);
          zp[mt][r] = z;  // 32-col partial per 16-lane group
        }
      if (lc == 0) {
#pragma unroll
        for (int mt = 0; mt < 2; ++mt)
          *(float4*)&zex[task][(wm * 4 + wn) * 8 + mt * 4 + lg][0] =
              make_float4(zp[mt][0], zp[mt][1], zp[mt][2], zp[mt][3]);
      }
      lds_bar();
#pragma unroll
      for (int mt = 0; mt < 2; ++mt) {
        float Z[4] = {0.f, 0.f, 0.f, 0.f};
#pragma unroll
        for (int w2 = 0; w2 < 4; ++w2) {
          float4 v = *(const float4*)&zex[task][(wm * 4 + w2) * 8 + mt * 4 + lg][0];
          Z[0] += v.x; Z[1] += v.y; Z[2] += v.z; Z[3] += v.w;
        }
#pragma unroll
        for (int r = 0; r < 4; ++r) {
          const int brow = wm * 32 + mt * 16 + lg * 4 + r;
          const float cv = is_r ? c_col[task][brow] : xm_col[task][brow];
          const float coef = cv * __builtin_amdgcn_rcpf(Z[r]);
          cpart[mt][0][r] += coef * ev[mt][0][r];
          cpart[mt][1][r] += coef * ev[mt][1][r];
        }
      }
    }

    // ---- deferred outputs for step t-1 (drain folds into end-of-step arrive) ----
    if (t > 0 && tid < 128) {
      hs_out[((size_t)(t - 1) * 256 + btile * 64 + rank) * 128 + p] = hOut;
      cs_out[((size_t)(t - 1) * 256 + btile * 64 + rank) * 128 + p] = c2Out;
    }

    // ---- bank store: quad butterfly (bit0 swap) -> u64 pair stores (r14) ----
    {
      float* bb = bank_mem + (size_t)(t & 1) * 2097152 + (size_t)btile * 524288 +
                  (size_t)rank * 8192;
      const int q1 = lc & 1;
      const int pq0 = wn * 32 + (lc & ~1);  // + nt*16 per nt
#pragma unroll
      for (int mt = 0; mt < 2; ++mt)
#pragma unroll
        for (int nt = 0; nt < 2; ++nt) {
          float a0 = cpart[mt][nt][0], a1 = cpart[mt][nt][1];
          float a2 = cpart[mt][nt][2], a3 = cpart[mt][nt][3];
          float t0 = __shfl_xor(a0, 1), t1 = __shfl_xor(a1, 1);
          float t2 = __shfl_xor(a2, 1), t3 = __shfl_xor(a3, 1);
          float b0 = q1 ? t1 : a0;   // row q1,   col lo
          float b1 = q1 ? a1 : t0;   // row q1,   col hi
          float b2 = q1 ? t3 : a2;   // row 2+q1, col lo
          float b3 = q1 ? a3 : t2;   // row 2+q1, col hi
          const int r1 = wm * 32 + mt * 16 + lg * 4 + q1;
          const int pq = pq0 + nt * 16;
          u64 pk1 = (u64)__float_as_uint(b0) | ((u64)__float_as_uint(b1) << 32);
          u64 pk2 = (u64)__float_as_uint(b2) | ((u64)__float_as_uint(b3) << 32);
          stc((u64*)(bb + (size_t)r1 * 128 + pq), pk1);
          stc((u64*)(bb + (size_t)(r1 + 2) * 128 + pq), pk2);
        }
    }

    // ---- arrive: drain vmem, one counter add to own oslot line ----
    asm volatile("s_waitcnt vmcnt(0)" ::: "memory");
    __builtin_amdgcn_s_barrier();
    __builtin_amdgcn_sched_barrier(0);
    if (tid == 0)
      __hip_atomic_fetch_add(scnt + oslot * 64, 1u, __ATOMIC_RELAXED, __HIP_MEMORY_SCOPE_AGENT);
  }
}

// ---------------- fallback: per-step kernel (round-1 proven path, ws-based) ----------------
__global__ __launch_bounds__(512, 2) void step_kernel(
    const float* __restrict__ xm, const float* __restrict__ xa,
    const float* __restrict__ br, const float* __restrict__ bi, const float* __restrict__ bo,
    const u16* __restrict__ WrB, const u16* __restrict__ WiB, const u16* __restrict__ WoB,
    float* __restrict__ c_acc, float* __restrict__ o_buf,
    float* __restrict__ hs_out, float* __restrict__ cs_out, int t) {
  __shared__ u16 W_lds[128][168];
  __shared__ u16 g_lds[64][160];

  const int tid = threadIdx.x;
  const int wg = blockIdx.x;
  const int xcd = wg & 7;
  const int l32 = wg >> 3;
  const int btile = l32 & 3;
  const int oslot = l32 >> 2;
  const int rank = oslot * 8 + xcd;
  const int orow0 = xcd * 24 + oslot * 3;

  const int lane = tid & 63;
  const int wv = tid >> 6;
  const int wm = wv >> 2;
  const int wn = wv & 3;
  const int lg = lane >> 4;
  const int lc = lane & 15;

  if (t < LSTEPS && tid < 32) {
    float4* zb = (float4*)(c_acc + ((t + 1) % 3) * 32768 + wg * 128);
    zb[tid] = make_float4(0.f, 0.f, 0.f, 0.f);
  }

  const int bloc = tid >> 3;
  const int seg = tid & 7;
  const int pseg = seg * 16;
  const int bg = btile * 64 + bloc;

  if (t > 0) {
    const float* ca = c_acc + ((t + 2) % 3) * 32768 + bg * 128 + pseg;
    const float* ol = o_buf + ((t + 1) & 1) * 32768 + bg * 128 + pseg;
    float hv[16], cc[16];
    float csum = 0.f;
#pragma unroll
    for (int q = 0; q < 4; ++q) {
      float4 cn = ((const float4*)ca)[q];
      float4 sl = ((const float4*)ol)[q];
      float cna[4] = {cn.x, cn.y, cn.z, cn.w};
      float sla[4] = {sl.x, sl.y, sl.z, sl.w};
#pragma unroll
      for (int j = 0; j < 4; ++j) {
        float e2 = __builtin_amdgcn_exp2f(sla[j]);
        float og = __builtin_amdgcn_rcpf(1.f + e2);
        float h = og * cna[j];
        float c2 = cna[j] - h;
        hv[q * 4 + j] = h;
        cc[q * 4 + j] = c2;
        csum += c2;
      }
    }
    csum += __shfl_xor(csum, 1);
    csum += __shfl_xor(csum, 2);
    csum += __shfl_xor(csum, 4);
    float sc = (csum == 0.f) ? 1.f : csum;
    float inv = __builtin_amdgcn_rcpf(sc);
    if (bloc == rank) {
      float* ho = hs_out + ((size_t)(t - 1) * 256 + bg) * 128 + pseg;
      float* co = cs_out + ((size_t)(t - 1) * 256 + bg) * 128 + pseg;
#pragma unroll
      for (int q = 0; q < 4; ++q) {
        ((float4*)ho)[q] = make_float4(hv[q * 4], hv[q * 4 + 1], hv[q * 4 + 2], hv[q * 4 + 3]);
        ((float4*)co)[q] = make_float4(cc[q * 4], cc[q * 4 + 1], cc[q * 4 + 2], cc[q * 4 + 3]);
      }
    }
    u32 w[8];
#pragma unroll
    for (int k = 0; k < 8; ++k)
      w[k] = (u32)f2bf(cc[2 * k] * inv) | ((u32)f2bf(cc[2 * k + 1] * inv) << 16);
    uint4* gdst = (uint4*)&g_lds[bloc][32 + pseg];
    gdst[0] = make_uint4(w[0], w[1], w[2], w[3]);
    gdst[1] = make_uint4(w[4], w[5], w[6], w[7]);
  } else {
    uint4* gdst = (uint4*)&g_lds[bloc][32 + pseg];
    gdst[0] = make_uint4(0, 0, 0, 0);
    gdst[1] = make_uint4(0, 0, 0, 0);
  }

  if (t == LSTEPS) return;

  {
    float4 xv = ((const float4*)(xa + ((size_t)t * 256 + bg) * 32))[seg];
    uint2 pk = make_uint2((u32)f2bf(xv.x) | ((u32)f2bf(xv.y) << 16),
                          (u32)f2bf(xv.z) | ((u32)f2bf(xv.w) << 16));
    *(uint2*)&g_lds[bloc][seg * 4] = pk;
  }
  __syncthreads();

  s8v afr[2][5];
#pragma unroll
  for (int mt = 0; mt < 2; ++mt)
#pragma unroll
    for (int ks = 0; ks < 5; ++ks)
      afr[mt][ks] = *(const s8v*)&g_lds[wm * 32 + mt * 16 + lc][ks * 32 + lg * 8];

  float cpart[2][2][4] = {};
  const float* cprev = c_acc + ((t + 2) % 3) * 32768;
  const float* oprev = o_buf + ((t + 1) & 1) * 32768;

  uint4 pf[5];
  {
    const u16* wbp = (orow0 < 128) ? (WrB + (size_t)orow0 * 20480)
                                   : (WiB + (size_t)(orow0 - 128) * 20480);
#pragma unroll
    for (int i = 0; i < 5; ++i) pf[i] = ((const uint4*)wbp)[tid + i * 512];
  }
#pragma unroll
  for (int i = 0; i < 5; ++i) {
    int chunk = tid + i * 512;
    *(uint4*)((char*)&W_lds[0][0] + (chunk / 20) * 336 + (chunk % 20) * 16) = pf[i];
  }
  __syncthreads();

  for (int task = 0; task < 3; ++task) {
    const int orow = orow0 + task;
    const bool is_r = (orow < 128);
    if (task < 2) {
      const int nr = orow + 1;
      const u16* wbp = (nr < 128) ? (WrB + (size_t)nr * 20480)
                                  : (WiB + (size_t)(nr - 128) * 20480);
#pragma unroll
      for (int i = 0; i < 5; ++i) pf[i] = ((const uint4*)wbp)[tid + i * 512];
    }
    const float* bptr = is_r ? (br + orow * 128) : (bi + (orow - 128) * 128);
    float bias0 = bptr[wn * 32 + lc] * LOG2E;
    float bias1 = bptr[wn * 32 + 16 + lc] * LOG2E;
    f4v acc[2][2];
#pragma unroll
    for (int mt = 0; mt < 2; ++mt) {
      acc[mt][0] = (f4v){bias0, bias0, bias0, bias0};
      acc[mt][1] = (f4v){bias1, bias1, bias1, bias1};
    }
#pragma unroll
    for (int ks = 0; ks < 5; ++ks) {
      s8v b0 = *(const s8v*)&W_lds[wn * 32 + lc][ks * 32 + lg * 8];
      s8v b1 = *(const s8v*)&W_lds[wn * 32 + 16 + lc][ks * 32 + lg * 8];
      acc[0][0] = __builtin_amdgcn_mfma_f32_16x16x32_bf16(afr[0][ks], b0, acc[0][0], 0, 0, 0);
      acc[1][0] = __builtin_amdgcn_mfma_f32_16x16x32_bf16(afr[1][ks], b0, acc[1][0], 0, 0, 0);
      acc[0][1] = __builtin_amdgcn_mfma_f32_16x16x32_bf16(afr[0][ks], b1, acc[0][1], 0, 0, 0);
      acc[1][1] = __builtin_amdgcn_mfma_f32_16x16x32_bf16(afr[1][ks], b1, acc[1][1], 0, 0, 0);
    }
    float ev[2][2][4];
    float zp[2][4];
#pragma unroll
    for (int mt = 0; mt < 2; ++mt)
#pragma unroll
      for (int r = 0; r < 4; ++r) {
        float e0 = __builtin_amdgcn_exp2f(acc[mt][0][r]);
        float e1 = __builtin_amdgcn_exp2f(acc[mt][1][r]);
        ev[mt][0][r] = e0;
        ev[mt][1][r] = e1;
        zp[mt][r] = e0 + e1;
      }
#pragma unroll
    for (int mt = 0; mt < 2; ++mt)
#pragma unroll
      for (int r = 0; r < 4; ++r) {
        float z = zp[mt][r];
        z += __shfl_xor(z, 1);
        z += __shfl_xor(z, 2);
        z += __shfl_xor(z, 4);
        z += __shfl_xor(z, 8);
        zp[mt][r] = z;
      }
    if (lc == 0) {
#pragma unroll
      for (int mt = 0; mt < 2; ++mt)
        *(float4*)((char*)&W_lds[0][0] + ((wm * 4 + wn) * 8 + mt * 4 + lg) * 336 + 320) =
            make_float4(zp[mt][0], zp[mt][1], zp[mt][2], zp[mt][3]);
    }
    __syncthreads();
#pragma unroll
    for (int mt = 0; mt < 2; ++mt) {
      float Z[4] = {0.f, 0.f, 0.f, 0.f};
#pragma unroll
      for (int w2 = 0; w2 < 4; ++w2) {
        float4 v = *(const float4*)((char*)&W_lds[0][0] + ((wm * 4 + w2) * 8 + mt * 4 + lg) * 336 + 320);
        Z[0] += v.x; Z[1] += v.y; Z[2] += v.z; Z[3] += v.w;
      }
#pragma unroll
      for (int r = 0; r < 4; ++r) {
        const int brow = wm * 32 + mt * 16 + lg * 4 + r;
        const int bg2 = btile * 64 + brow;
        float cv;
        if (is_r) {
          if (t > 0) {
            float cn = cprev[bg2 * 128 + orow];
            float s2 = oprev[bg2 * 128 + orow];
            float e2 = __builtin_amdgcn_exp2f(s2);
            cv = cn * e2 * __builtin_amdgcn_rcpf(1.f + e2);
          } else cv = 0.f;
        } else {
          cv = xm[((size_t)t * 256 + bg2) * 64 + (orow - 128)];
        }
        float coef = cv * __builtin_amdgcn_rcpf(Z[r]);
        cpart[mt][0][r] += coef * ev[mt][0][r];
        cpart[mt][1][r] += coef * ev[mt][1][r];
      }
    }
    if (task < 2) {
#pragma unroll
      for (int i = 0; i < 5; ++i) {
        int chunk = tid + i * 512;
        *(uint4*)((char*)&W_lds[0][0] + (chunk / 20) * 336 + (chunk % 20) * 16) = pf[i];
      }
      __syncthreads();
    }
  }

  if (oslot < 4 && xcd == ((oslot + 2 * btile) & 7) && wn == 0) {
    const int qoff = oslot * 32;
    float ob0 = bo[qoff + lc] * (-LOG2E);
    float ob1 = bo[qoff + 16 + lc] * (-LOG2E);
    f4v oacc[2][2];
#pragma unroll
    for (int mt = 0; mt < 2; ++mt) {
      oacc[mt][0] = (f4v){ob0, ob0, ob0, ob0};
      oacc[mt][1] = (f4v){ob1, ob1, ob1, ob1};
    }
#pragma unroll
    for (int ks = 0; ks < 5; ++ks) {
      s8v b0 = *(const s8v*)(WoB + (size_t)(qoff + lc) * 160 + ks * 32 + lg * 8);
      s8v b1 = *(const s8v*)(WoB + (size_t)(qoff + 16 + lc) * 160 + ks * 32 + lg * 8);
      oacc[0][0] = __builtin_amdgcn_mfma_f32_16x16x32_bf16(afr[0][ks], b0, oacc[0][0], 0, 0, 0);
      oacc[1][0] = __builtin_amdgcn_mfma_f32_16x16x32_bf16(afr[1][ks], b0, oacc[1][0], 0, 0, 0);
      oacc[0][1] = __builtin_amdgcn_mfma_f32_16x16x32_bf16(afr[0][ks], b1, oacc[0][1], 0, 0, 0);
      oacc[1][1] = __builtin_amdgcn_mfma_f32_16x16x32_bf16(afr[1][ks], b1, oacc[1][1], 0, 0, 0);
    }
    float* ob = o_buf + (t & 1) * 32768;
#pragma unroll
    for (int mt = 0; mt < 2; ++mt)
#pragma unroll
      for (int nt = 0; nt < 2; ++nt)
#pragma unroll
        for (int r = 0; r < 4; ++r)
          ob[(btile * 64 + wm * 32 + mt * 16 + lg * 4 + r) * 128 + qoff + nt * 16 + lc] = oacc[mt][nt][r];
  }

  float* cb = c_acc + (t % 3) * 32768;
#pragma unroll
  for (int mt = 0; mt < 2; ++mt)
#pragma unroll
    for (int nt = 0; nt < 2; ++nt)
#pragma unroll
      for (int r = 0; r < 4; ++r)
        unsafeAtomicAdd(&cb[(btile * 64 + wm * 32 + mt * 16 + lg * 4 + r) * 128 + wn * 32 + nt * 16 + lc],
                        cpart[mt][nt][r]);
}

extern "C" void kernel_launch(void* const* d_in, const int* in_sizes, int n_in,
                              void* d_out, int out_size, void* d_ws, size_t ws_size,
                              hipStream_t stream) {
  const float* xm = (const float*)d_in[0];
  const float* xa = (const float*)d_in[1];
  const float* Wr = (const float*)d_in[2];
  const float* br = (const float*)d_in[3];
  const float* Wi = (const float*)d_in[4];
  const float* bi = (const float*)d_in[5];
  const float* Wo = (const float*)d_in[6];
  const float* bo = (const float*)d_in[7];

  if (ws_size < 8560640) return;
  u16* WrB = (u16*)d_ws;
  u16* WiB = WrB + 16384 * 160;
  u16* WoB = WiB + 8192 * 160;
  float* c_acc = (float*)(WoB + 128 * 160);  // fallback-path accumulator
  float* o_buf = c_acc + 3 * 32768;

  float* hs = (float*)d_out;
  float* cs = hs + (size_t)LSTEPS * 256 * 128;

  convert_w_kernel<<<dim3(1024), dim3(256), 0, stream>>>(Wr, Wi, Wo, WrB, WiB, WoB);
  (void)hipMemsetAsync(c_acc, 0, 3 * 32768 * sizeof(float), stream);

  void* kargs[] = {(void*)&xm, (void*)&xa, (void*)&br, (void*)&bi, (void*)&bo,
                   (void*)&WrB, (void*)&WiB, (void*)&WoB,
                   (void*)&o_buf, (void*)&hs, (void*)&cs};
  hipError_t st = hipLaunchCooperativeKernel((const void*)persist_kernel, dim3(256), dim3(512),
                                             kargs, 0, stream);
  if (st != hipSuccess) {  // fallback: proven per-step path
    for (int t = 0; t <= LSTEPS; ++t)
      step_kernel<<<dim3(256), dim3(512), 0, stream>>>(xm, xa, br, bi, bo, WrB, WiB, WoB,
                                                       c_acc, o_buf, hs, cs, t);
  }
}